// Round 1
// baseline (372.926 us; speedup 1.0000x reference)
//
#include <hip/hip_runtime.h>

// Problem constants (from reference setup_inputs)
#define BB 16
#define SS 64
#define II 128
#define HH 512
#define TT 5          // NUM_TIMESTEPS
#define ALPHA 0.9f
#define THRESH 1.0f

// Kernel 1: cur[b,s,h] = sum_i x[b,s,i,h] * enc[i,h]
// One thread per float4 of cur. tid -> (bs, h4). Coalesced float4 loads.
__global__ __launch_bounds__(256) void einsum_kernel(const float4* __restrict__ x,
                                                     const float4* __restrict__ enc,
                                                     float4* __restrict__ cur) {
    const int H4 = HH / 4;                       // 128
    int tid = blockIdx.x * blockDim.x + threadIdx.x;   // 0 .. B*S*H4-1 (131072)
    int h4 = tid & (H4 - 1);
    int bs = tid >> 7;                           // b*S + s
    const float4* xp = x + (size_t)bs * (II * H4) + h4;
    float4 acc = make_float4(0.f, 0.f, 0.f, 0.f);
#pragma unroll 8
    for (int i = 0; i < II; ++i) {
        float4 xv = xp[(size_t)i * H4];
        float4 ev = enc[i * H4 + h4];
        acc.x = fmaf(xv.x, ev.x, acc.x);
        acc.y = fmaf(xv.y, ev.y, acc.y);
        acc.z = fmaf(xv.z, ev.z, acc.z);
        acc.w = fmaf(xv.w, ev.w, acc.w);
    }
    cur[tid] = acc;
}

// Kernel 2: LIF scan. One thread per (b,h) chain; 64 sequence positions x 5 steps.
// v = alpha*v + i_t; z = (v - 1 > 0); v -= z.
__global__ __launch_bounds__(64) void scan_kernel(const float* __restrict__ cur,
                                                  float* __restrict__ out) {
    int tid = blockIdx.x * blockDim.x + threadIdx.x;   // 0 .. B*H-1 (8192)
    int h = tid & (HH - 1);
    int b = tid >> 9;
    const float* cp = cur + (size_t)b * SS * HH + h;
    float* op = out + (size_t)b * (SS * TT) * HH + h;
    float v = 0.f;
    for (int s = 0; s < SS; ++s) {
        float it = cp[(size_t)s * HH];
#pragma unroll
        for (int t = 0; t < TT; ++t) {
            v = ALPHA * v + it;
            float z = (v > THRESH) ? 1.0f : 0.0f;
            op[(size_t)(s * TT + t) * HH] = z;
            v -= z;   // z*THRESH with THRESH==1
        }
    }
}

extern "C" void kernel_launch(void* const* d_in, const int* in_sizes, int n_in,
                              void* d_out, int out_size, void* d_ws, size_t ws_size,
                              hipStream_t stream) {
    const float* x   = (const float*)d_in[0];   // [B,S,I,H]
    const float* enc = (const float*)d_in[1];   // [I,H]
    float* out = (float*)d_out;                 // [B,S*T,H]
    float* cur = (float*)d_ws;                  // [B,S,H] scratch: 2 MB

    // Kernel 1: B*S*(H/4) = 131072 threads
    einsum_kernel<<<512, 256, 0, stream>>>((const float4*)x, (const float4*)enc,
                                           (float4*)cur);
    // Kernel 2: B*H = 8192 threads, spread across CUs as 128 single-wave blocks
    scan_kernel<<<128, 64, 0, stream>>>(cur, out);
}

// Round 3
// 367.299 us; speedup vs baseline: 1.0153x; 1.0153x over previous
//
#include <hip/hip_runtime.h>

// Problem constants (from reference setup_inputs)
#define BB 16
#define SS 64
#define II 128
#define HH 512
#define TT 5          // NUM_TIMESTEPS
#define ALPHA 0.9f
#define THRESH 1.0f

// Native clang vector type: __builtin_nontemporal_* requires a real vector,
// not HIP's struct float4.
typedef float v4f __attribute__((ext_vector_type(4)));

// Kernel 1: cur[b,s,h] = sum_i x[b,s,i,h] * enc[i,h]
// One thread per v4f of cur. tid -> (bs, h4). Coalesced 16B loads.
// x is 268 MB streamed exactly once -> non-temporal loads keep enc hot in L2.
__global__ __launch_bounds__(256) void einsum_kernel(const v4f* __restrict__ x,
                                                     const v4f* __restrict__ enc,
                                                     v4f* __restrict__ cur) {
    const int H4 = HH / 4;                       // 128
    int tid = blockIdx.x * blockDim.x + threadIdx.x;   // 0 .. B*S*H4-1 (131072)
    int h4 = tid & (H4 - 1);
    int bs = tid >> 7;                           // b*S + s
    const v4f* xp = x + (size_t)bs * (II * H4) + h4;
    const v4f* ep = enc + h4;
    v4f acc = (v4f)(0.f);
#pragma unroll 16
    for (int i = 0; i < II; ++i) {
        v4f xv = __builtin_nontemporal_load(&xp[(size_t)i * H4]);
        v4f ev = ep[(size_t)i * H4];
        acc.x = fmaf(xv.x, ev.x, acc.x);
        acc.y = fmaf(xv.y, ev.y, acc.y);
        acc.z = fmaf(xv.z, ev.z, acc.z);
        acc.w = fmaf(xv.w, ev.w, acc.w);
    }
    cur[tid] = acc;
}

// Kernel 2: LIF scan. One thread per 4 adjacent (b,h) chains (v4f):
// 4x ILP on the dependent v-chain, 2-deep prefetch of cur to hide L2/L3
// latency, non-temporal 16B stores (out is write-once streamed).
__global__ __launch_bounds__(64) void scan_kernel(const v4f* __restrict__ cur,
                                                  v4f* __restrict__ out) {
    const int H4 = HH / 4;                       // 128
    int tid = blockIdx.x * blockDim.x + threadIdx.x;   // 0 .. B*H4-1 (2048)
    int h4 = tid & (H4 - 1);
    int b = tid >> 7;
    const v4f* cp = cur + (size_t)b * SS * H4 + h4;
    v4f* op = out + (size_t)b * (SS * TT) * H4 + h4;

    v4f v = (v4f)(0.f);
    v4f it0 = cp[0];
    v4f it1 = cp[H4];           // s = 1
    for (int s = 0; s < SS; ++s) {
        v4f it = it0;
        it0 = it1;
        if (s + 2 < SS) it1 = cp[(size_t)(s + 2) * H4];
        v4f* o = op + (size_t)s * TT * H4;
#pragma unroll
        for (int t = 0; t < TT; ++t) {
            v.x = fmaf(ALPHA, v.x, it.x);
            v.y = fmaf(ALPHA, v.y, it.y);
            v.z = fmaf(ALPHA, v.z, it.z);
            v.w = fmaf(ALPHA, v.w, it.w);
            v4f z;
            z.x = (v.x > THRESH) ? 1.0f : 0.0f;
            z.y = (v.y > THRESH) ? 1.0f : 0.0f;
            z.z = (v.z > THRESH) ? 1.0f : 0.0f;
            z.w = (v.w > THRESH) ? 1.0f : 0.0f;
            v.x -= z.x;  v.y -= z.y;  v.z -= z.z;  v.w -= z.w;
            __builtin_nontemporal_store(z, &o[(size_t)t * H4]);
        }
    }
}

extern "C" void kernel_launch(void* const* d_in, const int* in_sizes, int n_in,
                              void* d_out, int out_size, void* d_ws, size_t ws_size,
                              hipStream_t stream) {
    const float* x   = (const float*)d_in[0];   // [B,S,I,H]
    const float* enc = (const float*)d_in[1];   // [I,H]
    float* out = (float*)d_out;                 // [B,S*T,H]
    float* cur = (float*)d_ws;                  // [B,S,H] scratch: 2 MB

    // Kernel 1: B*S*(H/4) = 131072 threads
    einsum_kernel<<<512, 256, 0, stream>>>((const v4f*)x, (const v4f*)enc,
                                           (v4f*)cur);
    // Kernel 2: B*(H/4) = 2048 threads as 32 single-wave blocks on 32 CUs
    scan_kernel<<<32, 64, 0, stream>>>((const v4f*)cur, (v4f*)out);
}

// Round 4
// 353.805 us; speedup vs baseline: 1.0540x; 1.0381x over previous
//
#include <hip/hip_runtime.h>

// Problem constants (from reference setup_inputs)
#define BB 16
#define SS 64
#define II 128
#define HH 512
#define TT 5          // NUM_TIMESTEPS
#define ALPHA 0.9f
#define THRESH 1.0f

// Native clang vector type: __builtin_nontemporal_* requires a real vector,
// not HIP's struct float4.
typedef float v4f __attribute__((ext_vector_type(4)));

// Kernel 1: cur[b,s,h] = sum_i x[b,s,i,h] * enc[i,h]
// One thread per v4f of cur. tid -> (bs, h4). Coalesced 16B loads.
// BW-bound: reads 268 MB of x exactly once -> floor ~42 us at 6.3 TB/s.
__global__ __launch_bounds__(256) void einsum_kernel(const v4f* __restrict__ x,
                                                     const v4f* __restrict__ enc,
                                                     v4f* __restrict__ cur) {
    const int H4 = HH / 4;                       // 128
    int tid = blockIdx.x * blockDim.x + threadIdx.x;   // 0 .. B*S*H4-1 (131072)
    int h4 = tid & (H4 - 1);
    int bs = tid >> 7;                           // b*S + s
    const v4f* xp = x + (size_t)bs * (II * H4) + h4;
    const v4f* ep = enc + h4;
    v4f acc = (v4f)(0.f);
#pragma unroll 16
    for (int i = 0; i < II; ++i) {
        v4f xv = __builtin_nontemporal_load(&xp[(size_t)i * H4]);
        v4f ev = ep[(size_t)i * H4];
        acc.x = fmaf(xv.x, ev.x, acc.x);
        acc.y = fmaf(xv.y, ev.y, acc.y);
        acc.z = fmaf(xv.z, ev.z, acc.z);
        acc.w = fmaf(xv.w, ev.w, acc.w);
    }
    cur[tid] = acc;
}

// Kernel 2: LIF scan. One SCALAR chain per thread, 8192 threads in 128
// blocks x 64 -> 128 CUs active. Per-CU HBM BW (~24.6 GB/s) is the store
// bottleneck: 10.5 MB / (128 CU x 24.6 GB/s) ~= 3.3 us floor. (R2's v4f
// variant used only 32 CUs -> 13 us floor; CU count beats per-thread ILP.)
// 2-deep prefetch hides cur load latency; NT stores avoid L2 write-alloc.
__global__ __launch_bounds__(64) void scan_kernel(const float* __restrict__ cur,
                                                  float* __restrict__ out) {
    int tid = blockIdx.x * blockDim.x + threadIdx.x;   // 0 .. B*H-1 (8192)
    int h = tid & (HH - 1);
    int b = tid >> 9;
    const float* cp = cur + (size_t)b * SS * HH + h;
    float* op = out + (size_t)b * (SS * TT) * HH + h;

    float v = 0.f;
    float it0 = cp[0];
    float it1 = cp[HH];            // s = 1
    for (int s = 0; s < SS; ++s) {
        float it = it0;
        it0 = it1;
        if (s + 2 < SS) it1 = cp[(size_t)(s + 2) * HH];
        float* o = op + (size_t)s * TT * HH;
#pragma unroll
        for (int t = 0; t < TT; ++t) {
            v = fmaf(ALPHA, v, it);
            float z = (v > THRESH) ? 1.0f : 0.0f;
            v -= z;
            __builtin_nontemporal_store(z, &o[(size_t)t * HH]);
        }
    }
}

extern "C" void kernel_launch(void* const* d_in, const int* in_sizes, int n_in,
                              void* d_out, int out_size, void* d_ws, size_t ws_size,
                              hipStream_t stream) {
    const float* x   = (const float*)d_in[0];   // [B,S,I,H]
    const float* enc = (const float*)d_in[1];   // [I,H]
    float* out = (float*)d_out;                 // [B,S*T,H]
    float* cur = (float*)d_ws;                  // [B,S,H] scratch: 2 MB

    // Kernel 1: B*S*(H/4) = 131072 threads
    einsum_kernel<<<512, 256, 0, stream>>>((const v4f*)x, (const v4f*)enc,
                                           (v4f*)cur);
    // Kernel 2: B*H = 8192 threads as 128 single-wave blocks -> 128 CUs
    scan_kernel<<<128, 64, 0, stream>>>(cur, out);
}